// Round 1
// baseline (3646.067 us; speedup 1.0000x reference)
//
#include <hip/hip_runtime.h>

#define NPTS 4096
#define NPT  1024
#define BATCH 16

// ---------------------------------------------------------------------------
// Farthest point sampling: one block per batch element. xyz staged in LDS.
// Bit-exact replication of the reference: dist init 1e10, d = ((dx*dx+dy*dy)+dz*dz)
// with no FMA contraction, argmax = first max (smallest index on ties).
// ---------------------------------------------------------------------------
__global__ __launch_bounds__(512) void fps_kernel(
    const float* __restrict__ xyz,
    float* __restrict__ out_nxyz,   // [B,1024,3]
    float* __restrict__ out_idxf)   // [B,1024] (indices stored as float)
{
    __shared__ float sx[NPTS], sy[NPTS], sz[NPTS];
    __shared__ float pv[8];
    __shared__ int   pi[8];
    __shared__ int   s_last;

    const int tid  = threadIdx.x;
    const int b    = blockIdx.x;
    const int lane = tid & 63;
    const int wid  = tid >> 6;

    const float* bx = xyz + (size_t)b * NPTS * 3;
    for (int p = tid; p < NPTS; p += 512) {
        sx[p] = bx[3 * p];
        sy[p] = bx[3 * p + 1];
        sz[p] = bx[3 * p + 2];
    }
    __syncthreads();

    float dist[8];
#pragma unroll
    for (int j = 0; j < 8; ++j) dist[j] = 1e10f;

    int last = 0;
    if (tid == 0) {
        out_idxf[b * NPT] = 0.0f;
        out_nxyz[(size_t)(b * NPT) * 3 + 0] = sx[0];
        out_nxyz[(size_t)(b * NPT) * 3 + 1] = sy[0];
        out_nxyz[(size_t)(b * NPT) * 3 + 2] = sz[0];
    }

    for (int step = 1; step < NPT; ++step) {
        const float lx = sx[last], ly = sy[last], lz = sz[last];
        float bv = -1.0f;
        int   bi = 0;
#pragma unroll
        for (int j = 0; j < 8; ++j) {
            const int p = tid + j * 512;
            const float dx = __fsub_rn(sx[p], lx);
            const float dy = __fsub_rn(sy[p], ly);
            const float dz = __fsub_rn(sz[p], lz);
            const float d  = __fadd_rn(__fadd_rn(__fmul_rn(dx, dx), __fmul_rn(dy, dy)),
                                       __fmul_rn(dz, dz));
            const float nd = fminf(dist[j], d);
            dist[j] = nd;
            if (nd > bv || (nd == bv && p < bi)) { bv = nd; bi = p; }
        }
        // wave butterfly argmax (tie -> smaller index)
#pragma unroll
        for (int off = 1; off < 64; off <<= 1) {
            const float ov = __shfl_xor(bv, off);
            const int   oi = __shfl_xor(bi, off);
            if (ov > bv || (ov == bv && oi < bi)) { bv = ov; bi = oi; }
        }
        if (lane == 0) { pv[wid] = bv; pi[wid] = bi; }
        __syncthreads();
        if (tid == 0) {
            float v  = pv[0];
            int   ix = pi[0];
#pragma unroll
            for (int w = 1; w < 8; ++w) {
                if (pv[w] > v || (pv[w] == v && pi[w] < ix)) { v = pv[w]; ix = pi[w]; }
            }
            s_last = ix;
            out_idxf[b * NPT + step] = (float)ix;
            out_nxyz[(size_t)(b * NPT + step) * 3 + 0] = sx[ix];
            out_nxyz[(size_t)(b * NPT + step) * 3 + 1] = sy[ix];
            out_nxyz[(size_t)(b * NPT + step) * 3 + 2] = sz[ix];
        }
        __syncthreads();
        last = s_last;
    }
}

// ---------------------------------------------------------------------------
// Per-scale: ball query + gather + 3-layer MLP + max-pool.
// Lane partition: k = lane % K (neighbor slot), qsub = lane / K (query in wave).
// Activations live in per-lane LDS columns (dynamic index safe); accumulators
// are full-FOUT register arrays with statically-unrolled indexing.
// ---------------------------------------------------------------------------
template <int CIN, int FOUT, int NT>
__device__ __forceinline__ void mlp_mid(const float* __restrict__ W,
                                        float* __restrict__ act, int tid)
{
    float acc[FOUT];
#pragma unroll
    for (int f = 0; f < FOUT; ++f) acc[f] = 0.0f;
#pragma unroll 1
    for (int c = 0; c < CIN; ++c) {
        const float xc = act[c * NT + tid];
        const float4* __restrict__ wr = (const float4*)(W + (size_t)c * FOUT);
#pragma unroll
        for (int j = 0; j < FOUT / 4; ++j) {
            const float4 w = wr[j];
            acc[4 * j + 0] = fmaf(xc, w.x, acc[4 * j + 0]);
            acc[4 * j + 1] = fmaf(xc, w.y, acc[4 * j + 1]);
            acc[4 * j + 2] = fmaf(xc, w.z, acc[4 * j + 2]);
            acc[4 * j + 3] = fmaf(xc, w.w, acc[4 * j + 3]);
        }
    }
    // relu + write back into activation columns (reads all done above)
#pragma unroll
    for (int f = 0; f < FOUT; ++f) act[f * NT + tid] = fmaxf(acc[f], 0.0f);
}

template <int CIN, int FOUT, int NT, int K>
__device__ __forceinline__ void mlp_final(const float* __restrict__ W,
                                          const float* __restrict__ act, int tid,
                                          int k, float* __restrict__ outp)
{
    float acc[FOUT];
#pragma unroll
    for (int f = 0; f < FOUT; ++f) acc[f] = 0.0f;
#pragma unroll 1
    for (int c = 0; c < CIN; ++c) {
        const float xc = act[c * NT + tid];
        const float4* __restrict__ wr = (const float4*)(W + (size_t)c * FOUT);
#pragma unroll
        for (int j = 0; j < FOUT / 4; ++j) {
            const float4 w = wr[j];
            acc[4 * j + 0] = fmaf(xc, w.x, acc[4 * j + 0]);
            acc[4 * j + 1] = fmaf(xc, w.y, acc[4 * j + 1]);
            acc[4 * j + 2] = fmaf(xc, w.z, acc[4 * j + 2]);
            acc[4 * j + 3] = fmaf(xc, w.w, acc[4 * j + 3]);
        }
    }
#pragma unroll
    for (int f = 0; f < FOUT; ++f) acc[f] = fmaxf(acc[f], 0.0f);
    // max-pool across the K-lane neighbor group (butterfly)
#pragma unroll
    for (int off = 1; off < K; off <<= 1) {
#pragma unroll
        for (int f = 0; f < FOUT; ++f)
            acc[f] = fmaxf(acc[f], __shfl_xor(acc[f], off));
    }
    if (k == 0) {
        float4* o = (float4*)outp;
#pragma unroll
        for (int j = 0; j < FOUT / 4; ++j)
            o[j] = make_float4(acc[4 * j + 0], acc[4 * j + 1], acc[4 * j + 2], acc[4 * j + 3]);
    }
}

template <int K, int F0, int F1, int F2, int CMAX, int CH_OFF, int NT>
__global__ __launch_bounds__(NT) void sa_kernel(
    const float* __restrict__ xyz,
    const float* __restrict__ points,
    const float* __restrict__ newxyz,   // read back from d_out region 0
    const float* __restrict__ w0,
    const float* __restrict__ w1,
    const float* __restrict__ w2,
    float* __restrict__ out1,
    float r2)
{
    constexpr int QPW = 64 / K;
    constexpr int NW  = NT / 64;
    constexpr unsigned long long KMASK =
        (K == 64) ? ~0ULL : ((1ULL << K) - 1ULL);

    __shared__ float act[CMAX * NT];
    __shared__ int   slist[NT];   // NW * QPW * K == NT

    const int tid  = threadIdx.x;
    const int lane = tid & 63;
    const int wid  = tid >> 6;
    const int k    = lane & (K - 1);
    const int qsub = lane / K;
    const int qid  = (blockIdx.x * NW + wid) * QPW + qsub;
    const int b    = qid >> 10;

    const float qx = newxyz[(size_t)qid * 3 + 0];
    const float qy = newxyz[(size_t)qid * 3 + 1];
    const float qz = newxyz[(size_t)qid * 3 + 2];
    const float* bxyz = xyz + (size_t)b * NPTS * 3;

    // ---- ball query: first K in-ball indices in ascending order ----
    int cnt = 0;
    const int gbase = (wid * QPW + qsub) * K;
    for (int c0 = 0; c0 < NPTS; c0 += K) {
        bool hit = false;
        const int p = c0 + k;
        if (cnt < K) {
            const float dx = __fsub_rn(qx, bxyz[3 * p]);
            const float dy = __fsub_rn(qy, bxyz[3 * p + 1]);
            const float dz = __fsub_rn(qz, bxyz[3 * p + 2]);
            const float d2 = __fadd_rn(__fadd_rn(__fmul_rn(dx, dx), __fmul_rn(dy, dy)),
                                       __fmul_rn(dz, dz));
            hit = d2 < r2;
        }
        const unsigned long long bal = __ballot(hit);
        const unsigned long long gm  = (bal >> (qsub * K)) & KMASK;
        const int pre = __popcll(gm & ((1ULL << k) - 1ULL));
        const int pos = cnt + pre;
        if (hit && pos < K) slist[gbase + pos] = p;
        cnt = min(cnt + (int)__popcll(gm), K);
        if (__all(cnt >= K)) break;
    }
    const int nbr = slist[gbase + ((k < cnt) ? k : 0)];

    // ---- gather: 16 point features + 3 relative xyz into LDS column ----
    {
        const float4* prow = (const float4*)(points + ((size_t)b * NPTS + nbr) * 16);
        const float4 a0 = prow[0], a1 = prow[1], a2 = prow[2], a3 = prow[3];
        act[0 * NT + tid] = a0.x;  act[1 * NT + tid] = a0.y;
        act[2 * NT + tid] = a0.z;  act[3 * NT + tid] = a0.w;
        act[4 * NT + tid] = a1.x;  act[5 * NT + tid] = a1.y;
        act[6 * NT + tid] = a1.z;  act[7 * NT + tid] = a1.w;
        act[8 * NT + tid] = a2.x;  act[9 * NT + tid] = a2.y;
        act[10 * NT + tid] = a2.z; act[11 * NT + tid] = a2.w;
        act[12 * NT + tid] = a3.x; act[13 * NT + tid] = a3.y;
        act[14 * NT + tid] = a3.z; act[15 * NT + tid] = a3.w;
        act[16 * NT + tid] = __fsub_rn(bxyz[3 * nbr],     qx);
        act[17 * NT + tid] = __fsub_rn(bxyz[3 * nbr + 1], qy);
        act[18 * NT + tid] = __fsub_rn(bxyz[3 * nbr + 2], qz);
    }

    // ---- MLP ----
    mlp_mid<19, F0, NT>(w0, act, tid);
    mlp_mid<F0, F1, NT>(w1, act, tid);
    float* outp = out1 + (size_t)qid * 320 + CH_OFF;
    mlp_final<F1, F2, NT, K>(w2, act, tid, k, outp);
}

// ---------------------------------------------------------------------------
extern "C" void kernel_launch(void* const* d_in, const int* in_sizes, int n_in,
                              void* d_out, int out_size, void* d_ws, size_t ws_size,
                              hipStream_t stream)
{
    const float* xyz    = (const float*)d_in[0];
    const float* points = (const float*)d_in[1];
    const float* w00 = (const float*)d_in[2];
    const float* w01 = (const float*)d_in[3];
    const float* w02 = (const float*)d_in[4];
    const float* w10 = (const float*)d_in[5];
    const float* w11 = (const float*)d_in[6];
    const float* w12 = (const float*)d_in[7];
    const float* w20 = (const float*)d_in[8];
    const float* w21 = (const float*)d_in[9];
    const float* w22 = (const float*)d_in[10];

    float* out       = (float*)d_out;
    float* out_nxyz  = out;                       // 16*1024*3   = 49152
    float* out_feat  = out + 49152;               // 16*1024*320 = 5242880
    float* out_idxf  = out + 49152 + 5242880;     // 16*1024     = 16384

    fps_kernel<<<BATCH, 512, 0, stream>>>(xyz, out_nxyz, out_idxf);

    // scale 0: r=0.1, K=16, MLP 19->32->32->64, CH_OFF 0
    sa_kernel<16, 32, 32, 64, 32, 0, 256><<<1024, 256, 0, stream>>>(
        xyz, points, out_nxyz, w00, w01, w02, out_feat, (float)(0.1 * 0.1));
    // scale 1: r=0.2, K=32, MLP 19->64->64->128, CH_OFF 64
    sa_kernel<32, 64, 64, 128, 64, 64, 128><<<4096, 128, 0, stream>>>(
        xyz, points, out_nxyz, w10, w11, w12, out_feat, (float)(0.2 * 0.2));
    // scale 2: r=0.4, K=64, MLP 19->64->96->128, 96, 192, CH_OFF 192
    sa_kernel<64, 64, 96, 128, 96, 192, 128><<<8192, 128, 0, stream>>>(
        xyz, points, out_nxyz, w20, w21, w22, out_feat, (float)(0.4 * 0.4));
}

// Round 2
// 3387.481 us; speedup vs baseline: 1.0763x; 1.0763x over previous
//
#include <hip/hip_runtime.h>

#define NPTS 4096
#define NPT  1024
#define BATCH 16

// ---------------------------------------------------------------------------
// Farthest point sampling: one block per batch element.
// Point coords + running min-dist live in REGISTERS (8 pts/thread, 512 thr);
// LDS keeps a staged xyz copy only for the per-step broadcast lookup of the
// chosen point. One barrier per step via parity-double-buffered candidates.
// Bit-exact vs reference: no-FMA ((dx*dx+dy*dy)+dz*dz), fminf, first-max ties.
// ---------------------------------------------------------------------------
__global__ __launch_bounds__(512) void fps_kernel(
    const float* __restrict__ xyz,
    float* __restrict__ out_nxyz,   // [B,1024,3]
    float* __restrict__ out_idxf)   // [B,1024] (indices stored as float)
{
    __shared__ float sx[NPTS], sy[NPTS], sz[NPTS];
    __shared__ float pv[2][8];
    __shared__ int   pi[2][8];

    const int tid  = threadIdx.x;
    const int b    = blockIdx.x;
    const int lane = tid & 63;
    const int wid  = tid >> 6;

    const float* bx = xyz + (size_t)b * NPTS * 3;
    for (int p = tid; p < NPTS; p += 512) {
        sx[p] = bx[3 * p];
        sy[p] = bx[3 * p + 1];
        sz[p] = bx[3 * p + 2];
    }
    __syncthreads();

    float rx[8], ry[8], rz[8], dist[8];
#pragma unroll
    for (int j = 0; j < 8; ++j) {
        const int p = tid + j * 512;
        rx[j] = sx[p];
        ry[j] = sy[p];
        rz[j] = sz[p];
        dist[j] = 1e10f;
    }

    if (tid == 0) {
        out_idxf[b * NPT] = 0.0f;
        out_nxyz[(size_t)(b * NPT) * 3 + 0] = sx[0];
        out_nxyz[(size_t)(b * NPT) * 3 + 1] = sy[0];
        out_nxyz[(size_t)(b * NPT) * 3 + 2] = sz[0];
    }

    float lx = sx[0], ly = sy[0], lz = sz[0];

    for (int step = 1; step < NPT; ++step) {
        float bv = -1.0f;
        int   bi = 0;
#pragma unroll
        for (int j = 0; j < 8; ++j) {
            const int p = tid + j * 512;
            const float dx = __fsub_rn(rx[j], lx);
            const float dy = __fsub_rn(ry[j], ly);
            const float dz = __fsub_rn(rz[j], lz);
            const float d  = __fadd_rn(__fadd_rn(__fmul_rn(dx, dx), __fmul_rn(dy, dy)),
                                       __fmul_rn(dz, dz));
            const float nd = fminf(dist[j], d);
            dist[j] = nd;
            if (nd > bv || (nd == bv && p < bi)) { bv = nd; bi = p; }
        }
        // wave butterfly argmax (tie -> smaller index)
#pragma unroll
        for (int off = 1; off < 64; off <<= 1) {
            const float ov = __shfl_xor(bv, off);
            const int   oi = __shfl_xor(bi, off);
            if (ov > bv || (ov == bv && oi < bi)) { bv = ov; bi = oi; }
        }
        const int par = step & 1;
        if (lane == 0) { pv[par][wid] = bv; pi[par][wid] = bi; }
        __syncthreads();
        // every thread reduces the 8 wave candidates (first-max tie-break)
        float v  = pv[par][0];
        int   ix = pi[par][0];
#pragma unroll
        for (int w = 1; w < 8; ++w) {
            const float wv = pv[par][w];
            const int   wi2 = pi[par][w];
            if (wv > v || (wv == v && wi2 < ix)) { v = wv; ix = wi2; }
        }
        lx = sx[ix];  // broadcast (same address across lanes)
        ly = sy[ix];
        lz = sz[ix];
        if (tid == 0) {
            out_idxf[b * NPT + step] = (float)ix;
            out_nxyz[(size_t)(b * NPT + step) * 3 + 0] = lx;
            out_nxyz[(size_t)(b * NPT + step) * 3 + 1] = ly;
            out_nxyz[(size_t)(b * NPT + step) * 3 + 2] = lz;
        }
        // no second barrier: next step writes the OTHER pv/pi buffer, and the
        // following barrier orders it against this step's reads.
    }
}

// ---------------------------------------------------------------------------
// Per-scale: ball query + gather + 3-layer MLP + max-pool.
// Lane partition: k = lane % K (neighbor slot), qsub = lane / K (query in wave).
// Activations live in per-lane LDS columns (dynamic index safe); accumulators
// are full-FOUT register arrays with statically-unrolled indexing.
// ---------------------------------------------------------------------------
template <int CIN, int FOUT, int NT>
__device__ __forceinline__ void mlp_mid(const float* __restrict__ W,
                                        float* __restrict__ act, int tid)
{
    float acc[FOUT];
#pragma unroll
    for (int f = 0; f < FOUT; ++f) acc[f] = 0.0f;
#pragma unroll 1
    for (int c = 0; c < CIN; ++c) {
        const float xc = act[c * NT + tid];
        const float4* __restrict__ wr = (const float4*)(W + (size_t)c * FOUT);
#pragma unroll
        for (int j = 0; j < FOUT / 4; ++j) {
            const float4 w = wr[j];
            acc[4 * j + 0] = fmaf(xc, w.x, acc[4 * j + 0]);
            acc[4 * j + 1] = fmaf(xc, w.y, acc[4 * j + 1]);
            acc[4 * j + 2] = fmaf(xc, w.z, acc[4 * j + 2]);
            acc[4 * j + 3] = fmaf(xc, w.w, acc[4 * j + 3]);
        }
    }
    // relu + write back into activation columns (reads all done above)
#pragma unroll
    for (int f = 0; f < FOUT; ++f) act[f * NT + tid] = fmaxf(acc[f], 0.0f);
}

template <int CIN, int FOUT, int NT, int K>
__device__ __forceinline__ void mlp_final(const float* __restrict__ W,
                                          const float* __restrict__ act, int tid,
                                          int k, float* __restrict__ outp)
{
    float acc[FOUT];
#pragma unroll
    for (int f = 0; f < FOUT; ++f) acc[f] = 0.0f;
#pragma unroll 1
    for (int c = 0; c < CIN; ++c) {
        const float xc = act[c * NT + tid];
        const float4* __restrict__ wr = (const float4*)(W + (size_t)c * FOUT);
#pragma unroll
        for (int j = 0; j < FOUT / 4; ++j) {
            const float4 w = wr[j];
            acc[4 * j + 0] = fmaf(xc, w.x, acc[4 * j + 0]);
            acc[4 * j + 1] = fmaf(xc, w.y, acc[4 * j + 1]);
            acc[4 * j + 2] = fmaf(xc, w.z, acc[4 * j + 2]);
            acc[4 * j + 3] = fmaf(xc, w.w, acc[4 * j + 3]);
        }
    }
#pragma unroll
    for (int f = 0; f < FOUT; ++f) acc[f] = fmaxf(acc[f], 0.0f);
    // max-pool across the K-lane neighbor group (butterfly)
#pragma unroll
    for (int off = 1; off < K; off <<= 1) {
#pragma unroll
        for (int f = 0; f < FOUT; ++f)
            acc[f] = fmaxf(acc[f], __shfl_xor(acc[f], off));
    }
    if (k == 0) {
        float4* o = (float4*)outp;
#pragma unroll
        for (int j = 0; j < FOUT / 4; ++j)
            o[j] = make_float4(acc[4 * j + 0], acc[4 * j + 1], acc[4 * j + 2], acc[4 * j + 3]);
    }
}

template <int K, int F0, int F1, int F2, int CMAX, int CH_OFF, int NT>
__global__ __launch_bounds__(NT) void sa_kernel(
    const float* __restrict__ xyz,
    const float* __restrict__ points,
    const float* __restrict__ newxyz,   // read back from d_out region 0
    const float* __restrict__ w0,
    const float* __restrict__ w1,
    const float* __restrict__ w2,
    float* __restrict__ out1,
    float r2)
{
    constexpr int QPW = 64 / K;
    constexpr int NW  = NT / 64;
    constexpr unsigned long long KMASK =
        (K == 64) ? ~0ULL : ((1ULL << K) - 1ULL);

    __shared__ float act[CMAX * NT];
    __shared__ int   slist[NT];   // NW * QPW * K == NT

    const int tid  = threadIdx.x;
    const int lane = tid & 63;
    const int wid  = tid >> 6;
    const int k    = lane & (K - 1);
    const int qsub = lane / K;
    const int qid  = (blockIdx.x * NW + wid) * QPW + qsub;
    const int b    = qid >> 10;

    const float qx = newxyz[(size_t)qid * 3 + 0];
    const float qy = newxyz[(size_t)qid * 3 + 1];
    const float qz = newxyz[(size_t)qid * 3 + 2];
    const float* bxyz = xyz + (size_t)b * NPTS * 3;

    // ---- ball query: first K in-ball indices in ascending order ----
    int cnt = 0;
    const int gbase = (wid * QPW + qsub) * K;
    for (int c0 = 0; c0 < NPTS; c0 += K) {
        bool hit = false;
        const int p = c0 + k;
        if (cnt < K) {
            const float dx = __fsub_rn(qx, bxyz[3 * p]);
            const float dy = __fsub_rn(qy, bxyz[3 * p + 1]);
            const float dz = __fsub_rn(qz, bxyz[3 * p + 2]);
            const float d2 = __fadd_rn(__fadd_rn(__fmul_rn(dx, dx), __fmul_rn(dy, dy)),
                                       __fmul_rn(dz, dz));
            hit = d2 < r2;
        }
        const unsigned long long bal = __ballot(hit);
        const unsigned long long gm  = (bal >> (qsub * K)) & KMASK;
        const int pre = __popcll(gm & ((1ULL << k) - 1ULL));
        const int pos = cnt + pre;
        if (hit && pos < K) slist[gbase + pos] = p;
        cnt = min(cnt + (int)__popcll(gm), K);
        if (__all(cnt >= K)) break;
    }
    const int nbr = slist[gbase + ((k < cnt) ? k : 0)];

    // ---- gather: 16 point features + 3 relative xyz into LDS column ----
    {
        const float4* prow = (const float4*)(points + ((size_t)b * NPTS + nbr) * 16);
        const float4 a0 = prow[0], a1 = prow[1], a2 = prow[2], a3 = prow[3];
        act[0 * NT + tid] = a0.x;  act[1 * NT + tid] = a0.y;
        act[2 * NT + tid] = a0.z;  act[3 * NT + tid] = a0.w;
        act[4 * NT + tid] = a1.x;  act[5 * NT + tid] = a1.y;
        act[6 * NT + tid] = a1.z;  act[7 * NT + tid] = a1.w;
        act[8 * NT + tid] = a2.x;  act[9 * NT + tid] = a2.y;
        act[10 * NT + tid] = a2.z; act[11 * NT + tid] = a2.w;
        act[12 * NT + tid] = a3.x; act[13 * NT + tid] = a3.y;
        act[14 * NT + tid] = a3.z; act[15 * NT + tid] = a3.w;
        act[16 * NT + tid] = __fsub_rn(bxyz[3 * nbr],     qx);
        act[17 * NT + tid] = __fsub_rn(bxyz[3 * nbr + 1], qy);
        act[18 * NT + tid] = __fsub_rn(bxyz[3 * nbr + 2], qz);
    }

    // ---- MLP ----
    mlp_mid<19, F0, NT>(w0, act, tid);
    mlp_mid<F0, F1, NT>(w1, act, tid);
    float* outp = out1 + (size_t)qid * 320 + CH_OFF;
    mlp_final<F1, F2, NT, K>(w2, act, tid, k, outp);
}

// ---------------------------------------------------------------------------
extern "C" void kernel_launch(void* const* d_in, const int* in_sizes, int n_in,
                              void* d_out, int out_size, void* d_ws, size_t ws_size,
                              hipStream_t stream)
{
    const float* xyz    = (const float*)d_in[0];
    const float* points = (const float*)d_in[1];
    const float* w00 = (const float*)d_in[2];
    const float* w01 = (const float*)d_in[3];
    const float* w02 = (const float*)d_in[4];
    const float* w10 = (const float*)d_in[5];
    const float* w11 = (const float*)d_in[6];
    const float* w12 = (const float*)d_in[7];
    const float* w20 = (const float*)d_in[8];
    const float* w21 = (const float*)d_in[9];
    const float* w22 = (const float*)d_in[10];

    float* out       = (float*)d_out;
    float* out_nxyz  = out;                       // 16*1024*3   = 49152
    float* out_feat  = out + 49152;               // 16*1024*320 = 5242880
    float* out_idxf  = out + 49152 + 5242880;     // 16*1024     = 16384

    fps_kernel<<<BATCH, 512, 0, stream>>>(xyz, out_nxyz, out_idxf);

    // scale 0: r=0.1, K=16, MLP 19->32->32->64, CH_OFF 0
    sa_kernel<16, 32, 32, 64, 32, 0, 256><<<1024, 256, 0, stream>>>(
        xyz, points, out_nxyz, w00, w01, w02, out_feat, (float)(0.1 * 0.1));
    // scale 1: r=0.2, K=32, MLP 19->64->64->128, CH_OFF 64
    sa_kernel<32, 64, 64, 128, 64, 64, 128><<<4096, 128, 0, stream>>>(
        xyz, points, out_nxyz, w10, w11, w12, out_feat, (float)(0.2 * 0.2));
    // scale 2: r=0.4, K=64, MLP 19->64->96->128, 96, 192, CH_OFF 192
    sa_kernel<64, 64, 96, 128, 96, 192, 128><<<8192, 128, 0, stream>>>(
        xyz, points, out_nxyz, w20, w21, w22, out_feat, (float)(0.4 * 0.4));
}

// Round 3
// 2860.840 us; speedup vs baseline: 1.2745x; 1.1841x over previous
//
#include <hip/hip_runtime.h>

#define NPTS 4096
#define NPT  1024
#define BATCH 16

// ---------------------------------------------------------------------------
// Farthest point sampling: one block per batch element.
// Coords + running min-dist in registers (8 pts/thread, 512 thr). Argmax is
// fully BRANCHLESS via packed u64 keys: (float_bits(dist)<<32) | ~idx.
// dist >= 0 so float bits are monotone; ~idx breaks ties toward smaller idx
// (== jnp.argmax first-max). Distance math identical to reference
// (no-FMA ((dx*dx+dy*dy)+dz*dz), fminf). One barrier/step via parity buffers.
// ---------------------------------------------------------------------------
__device__ __forceinline__ unsigned long long u64max(unsigned long long a,
                                                     unsigned long long b)
{
    return (a > b) ? a : b;   // v_cmp_lt_u64 + cndmask, branchless
}

__global__ __launch_bounds__(512) void fps_kernel(
    const float* __restrict__ xyz,
    float* __restrict__ out_nxyz,   // [B,1024,3]
    float* __restrict__ out_idxf)   // [B,1024] (indices stored as float)
{
    __shared__ float sx[NPTS], sy[NPTS], sz[NPTS];
    __shared__ unsigned long long pw[2][8];

    const int tid  = threadIdx.x;
    const int b    = blockIdx.x;
    const int lane = tid & 63;
    const int wid  = tid >> 6;

    const float* bx = xyz + (size_t)b * NPTS * 3;
    for (int p = tid; p < NPTS; p += 512) {
        sx[p] = bx[3 * p];
        sy[p] = bx[3 * p + 1];
        sz[p] = bx[3 * p + 2];
    }
    __syncthreads();

    float rx[8], ry[8], rz[8], dist[8];
#pragma unroll
    for (int j = 0; j < 8; ++j) {
        const int p = tid + j * 512;
        rx[j] = sx[p];
        ry[j] = sy[p];
        rz[j] = sz[p];
        dist[j] = 1e10f;
    }

    if (tid == 0) {
        out_idxf[b * NPT] = 0.0f;
        out_nxyz[(size_t)(b * NPT) * 3 + 0] = sx[0];
        out_nxyz[(size_t)(b * NPT) * 3 + 1] = sy[0];
        out_nxyz[(size_t)(b * NPT) * 3 + 2] = sz[0];
    }

    float lx = sx[0], ly = sy[0], lz = sz[0];

    for (int step = 1; step < NPT; ++step) {
        // ---- local 8-point update + branchless packed argmax ----
        unsigned long long best = 0ULL;
#pragma unroll
        for (int j = 0; j < 8; ++j) {
            const int p = tid + j * 512;
            const float dx = __fsub_rn(rx[j], lx);
            const float dy = __fsub_rn(ry[j], ly);
            const float dz = __fsub_rn(rz[j], lz);
            const float d  = __fadd_rn(__fadd_rn(__fmul_rn(dx, dx), __fmul_rn(dy, dy)),
                                       __fmul_rn(dz, dz));
            const float nd = fminf(dist[j], d);
            dist[j] = nd;
            const unsigned long long key =
                ((unsigned long long)__float_as_uint(nd) << 32) |
                (unsigned int)(~p);
            best = u64max(best, key);
        }
        // ---- wave butterfly max (branchless, 2x b32 shfl per step) ----
#pragma unroll
        for (int off = 1; off < 64; off <<= 1) {
            const unsigned int lo  = (unsigned int)best;
            const unsigned int hi  = (unsigned int)(best >> 32);
            const unsigned int olo = __shfl_xor(lo, off);
            const unsigned int ohi = __shfl_xor(hi, off);
            const unsigned long long o =
                ((unsigned long long)ohi << 32) | olo;
            best = u64max(best, o);
        }
        const int par = step & 1;
        if (lane == 0) pw[par][wid] = best;
        __syncthreads();
        // ---- every thread reduces the 8 wave winners (branchless) ----
        unsigned long long m = pw[par][0];
#pragma unroll
        for (int w = 1; w < 8; ++w) m = u64max(m, pw[par][w]);
        const int ix = (int)(~(unsigned int)m);

        lx = sx[ix];  // broadcast (same address across lanes)
        ly = sy[ix];
        lz = sz[ix];
        if (tid == 0) {
            out_idxf[b * NPT + step] = (float)ix;
            out_nxyz[(size_t)(b * NPT + step) * 3 + 0] = lx;
            out_nxyz[(size_t)(b * NPT + step) * 3 + 1] = ly;
            out_nxyz[(size_t)(b * NPT + step) * 3 + 2] = lz;
        }
        // single barrier per step: next step writes the other pw buffer.
    }
}

// ---------------------------------------------------------------------------
// Per-scale: ball query + gather + 3-layer MLP + max-pool.
// Activations in per-lane LDS columns (stride-1 across lanes: conflict-free).
// Channel loop unrolled x4: 4 independent ds_reads batched ahead of 4 FMA
// groups (per-accumulator c-order preserved -> bit-identical results).
// ---------------------------------------------------------------------------
template <int CIN, int FOUT, int NT>
__device__ __forceinline__ void mlp_body(const float* __restrict__ W,
                                         const float* __restrict__ act, int tid,
                                         float* __restrict__ acc)
{
#pragma unroll
    for (int f = 0; f < FOUT; ++f) acc[f] = 0.0f;
    constexpr int C4 = CIN & ~3;
#pragma unroll 2
    for (int c = 0; c < C4; c += 4) {
        const float x0 = act[(c + 0) * NT + tid];
        const float x1 = act[(c + 1) * NT + tid];
        const float x2 = act[(c + 2) * NT + tid];
        const float x3 = act[(c + 3) * NT + tid];
        const float4* __restrict__ w0r = (const float4*)(W + (size_t)(c + 0) * FOUT);
        const float4* __restrict__ w1r = (const float4*)(W + (size_t)(c + 1) * FOUT);
        const float4* __restrict__ w2r = (const float4*)(W + (size_t)(c + 2) * FOUT);
        const float4* __restrict__ w3r = (const float4*)(W + (size_t)(c + 3) * FOUT);
#pragma unroll
        for (int j = 0; j < FOUT / 4; ++j) {
            const float4 a = w0r[j];
            const float4 bb = w1r[j];
            const float4 cw = w2r[j];
            const float4 dw = w3r[j];
            float t0 = acc[4 * j + 0], t1 = acc[4 * j + 1];
            float t2 = acc[4 * j + 2], t3 = acc[4 * j + 3];
            t0 = fmaf(x0, a.x, t0);  t1 = fmaf(x0, a.y, t1);
            t2 = fmaf(x0, a.z, t2);  t3 = fmaf(x0, a.w, t3);
            t0 = fmaf(x1, bb.x, t0); t1 = fmaf(x1, bb.y, t1);
            t2 = fmaf(x1, bb.z, t2); t3 = fmaf(x1, bb.w, t3);
            t0 = fmaf(x2, cw.x, t0); t1 = fmaf(x2, cw.y, t1);
            t2 = fmaf(x2, cw.z, t2); t3 = fmaf(x2, cw.w, t3);
            t0 = fmaf(x3, dw.x, t0); t1 = fmaf(x3, dw.y, t1);
            t2 = fmaf(x3, dw.z, t2); t3 = fmaf(x3, dw.w, t3);
            acc[4 * j + 0] = t0; acc[4 * j + 1] = t1;
            acc[4 * j + 2] = t2; acc[4 * j + 3] = t3;
        }
    }
#pragma unroll
    for (int c = C4; c < CIN; ++c) {
        const float xc = act[c * NT + tid];
        const float4* __restrict__ wr = (const float4*)(W + (size_t)c * FOUT);
#pragma unroll
        for (int j = 0; j < FOUT / 4; ++j) {
            const float4 w = wr[j];
            acc[4 * j + 0] = fmaf(xc, w.x, acc[4 * j + 0]);
            acc[4 * j + 1] = fmaf(xc, w.y, acc[4 * j + 1]);
            acc[4 * j + 2] = fmaf(xc, w.z, acc[4 * j + 2]);
            acc[4 * j + 3] = fmaf(xc, w.w, acc[4 * j + 3]);
        }
    }
}

template <int CIN, int FOUT, int NT>
__device__ __forceinline__ void mlp_mid(const float* __restrict__ W,
                                        float* __restrict__ act, int tid)
{
    float acc[FOUT];
    mlp_body<CIN, FOUT, NT>(W, act, tid, acc);
#pragma unroll
    for (int f = 0; f < FOUT; ++f) act[f * NT + tid] = fmaxf(acc[f], 0.0f);
}

template <int CIN, int FOUT, int NT, int K>
__device__ __forceinline__ void mlp_final(const float* __restrict__ W,
                                          const float* __restrict__ act, int tid,
                                          int k, float* __restrict__ outp)
{
    float acc[FOUT];
    mlp_body<CIN, FOUT, NT>(W, act, tid, acc);
#pragma unroll
    for (int f = 0; f < FOUT; ++f) acc[f] = fmaxf(acc[f], 0.0f);
    // max-pool across the K-lane neighbor group (butterfly)
#pragma unroll
    for (int off = 1; off < K; off <<= 1) {
#pragma unroll
        for (int f = 0; f < FOUT; ++f)
            acc[f] = fmaxf(acc[f], __shfl_xor(acc[f], off));
    }
    if (k == 0) {
        float4* o = (float4*)outp;
#pragma unroll
        for (int j = 0; j < FOUT / 4; ++j)
            o[j] = make_float4(acc[4 * j + 0], acc[4 * j + 1], acc[4 * j + 2], acc[4 * j + 3]);
    }
}

template <int K, int F0, int F1, int F2, int CMAX, int CH_OFF, int NT>
__global__ __launch_bounds__(NT) void sa_kernel(
    const float* __restrict__ xyz,
    const float* __restrict__ points,
    const float* __restrict__ newxyz,   // read back from d_out region 0
    const float* __restrict__ w0,
    const float* __restrict__ w1,
    const float* __restrict__ w2,
    float* __restrict__ out1,
    float r2)
{
    constexpr int QPW = 64 / K;
    constexpr int NW  = NT / 64;
    constexpr unsigned long long KMASK =
        (K == 64) ? ~0ULL : ((1ULL << K) - 1ULL);

    __shared__ float act[CMAX * NT];
    __shared__ int   slist[NT];   // NW * QPW * K == NT

    const int tid  = threadIdx.x;
    const int lane = tid & 63;
    const int wid  = tid >> 6;
    const int k    = lane & (K - 1);
    const int qsub = lane / K;
    const int qid  = (blockIdx.x * NW + wid) * QPW + qsub;
    const int b    = qid >> 10;

    const float qx = newxyz[(size_t)qid * 3 + 0];
    const float qy = newxyz[(size_t)qid * 3 + 1];
    const float qz = newxyz[(size_t)qid * 3 + 2];
    const float* bxyz = xyz + (size_t)b * NPTS * 3;

    // ---- ball query: first K in-ball indices in ascending order ----
    int cnt = 0;
    const int gbase = (wid * QPW + qsub) * K;
    for (int c0 = 0; c0 < NPTS; c0 += K) {
        bool hit = false;
        const int p = c0 + k;
        if (cnt < K) {
            const float dx = __fsub_rn(qx, bxyz[3 * p]);
            const float dy = __fsub_rn(qy, bxyz[3 * p + 1]);
            const float dz = __fsub_rn(qz, bxyz[3 * p + 2]);
            const float d2 = __fadd_rn(__fadd_rn(__fmul_rn(dx, dx), __fmul_rn(dy, dy)),
                                       __fmul_rn(dz, dz));
            hit = d2 < r2;
        }
        const unsigned long long bal = __ballot(hit);
        const unsigned long long gm  = (bal >> (qsub * K)) & KMASK;
        const int pre = __popcll(gm & ((1ULL << k) - 1ULL));
        const int pos = cnt + pre;
        if (hit && pos < K) slist[gbase + pos] = p;
        cnt = min(cnt + (int)__popcll(gm), K);
        if (__all(cnt >= K)) break;
    }
    const int nbr = slist[gbase + ((k < cnt) ? k : 0)];

    // ---- gather: 16 point features + 3 relative xyz into LDS column ----
    {
        const float4* prow = (const float4*)(points + ((size_t)b * NPTS + nbr) * 16);
        const float4 a0 = prow[0], a1 = prow[1], a2 = prow[2], a3 = prow[3];
        act[0 * NT + tid] = a0.x;  act[1 * NT + tid] = a0.y;
        act[2 * NT + tid] = a0.z;  act[3 * NT + tid] = a0.w;
        act[4 * NT + tid] = a1.x;  act[5 * NT + tid] = a1.y;
        act[6 * NT + tid] = a1.z;  act[7 * NT + tid] = a1.w;
        act[8 * NT + tid] = a2.x;  act[9 * NT + tid] = a2.y;
        act[10 * NT + tid] = a2.z; act[11 * NT + tid] = a2.w;
        act[12 * NT + tid] = a3.x; act[13 * NT + tid] = a3.y;
        act[14 * NT + tid] = a3.z; act[15 * NT + tid] = a3.w;
        act[16 * NT + tid] = __fsub_rn(bxyz[3 * nbr],     qx);
        act[17 * NT + tid] = __fsub_rn(bxyz[3 * nbr + 1], qy);
        act[18 * NT + tid] = __fsub_rn(bxyz[3 * nbr + 2], qz);
    }

    // ---- MLP ----
    mlp_mid<19, F0, NT>(w0, act, tid);
    mlp_mid<F0, F1, NT>(w1, act, tid);
    float* outp = out1 + (size_t)qid * 320 + CH_OFF;
    mlp_final<F1, F2, NT, K>(w2, act, tid, k, outp);
}

// ---------------------------------------------------------------------------
extern "C" void kernel_launch(void* const* d_in, const int* in_sizes, int n_in,
                              void* d_out, int out_size, void* d_ws, size_t ws_size,
                              hipStream_t stream)
{
    const float* xyz    = (const float*)d_in[0];
    const float* points = (const float*)d_in[1];
    const float* w00 = (const float*)d_in[2];
    const float* w01 = (const float*)d_in[3];
    const float* w02 = (const float*)d_in[4];
    const float* w10 = (const float*)d_in[5];
    const float* w11 = (const float*)d_in[6];
    const float* w12 = (const float*)d_in[7];
    const float* w20 = (const float*)d_in[8];
    const float* w21 = (const float*)d_in[9];
    const float* w22 = (const float*)d_in[10];

    float* out       = (float*)d_out;
    float* out_nxyz  = out;                       // 16*1024*3   = 49152
    float* out_feat  = out + 49152;               // 16*1024*320 = 5242880
    float* out_idxf  = out + 49152 + 5242880;     // 16*1024     = 16384

    fps_kernel<<<BATCH, 512, 0, stream>>>(xyz, out_nxyz, out_idxf);

    // scale 0: r=0.1, K=16, MLP 19->32->32->64, CH_OFF 0
    sa_kernel<16, 32, 32, 64, 32, 0, 256><<<1024, 256, 0, stream>>>(
        xyz, points, out_nxyz, w00, w01, w02, out_feat, (float)(0.1 * 0.1));
    // scale 1: r=0.2, K=32, MLP 19->64->64->128, CH_OFF 64
    sa_kernel<32, 64, 64, 128, 64, 64, 128><<<4096, 128, 0, stream>>>(
        xyz, points, out_nxyz, w10, w11, w12, out_feat, (float)(0.2 * 0.2));
    // scale 2: r=0.4, K=64, MLP 19->64->96->128, 96, 192, CH_OFF 192
    sa_kernel<64, 64, 96, 128, 96, 192, 128><<<8192, 128, 0, stream>>>(
        xyz, points, out_nxyz, w20, w21, w22, out_feat, (float)(0.4 * 0.4));
}

// Round 4
// 2038.420 us; speedup vs baseline: 1.7887x; 1.4035x over previous
//
#include <hip/hip_runtime.h>

#define NPTS 4096
#define NPT  1024
#define BATCH 16

// ---------------------------------------------------------------------------
// Farthest point sampling: one block per batch element.
// Coords + running min-dist in registers (8 pts/thread, 512 thr). Argmax is
// fully BRANCHLESS via packed u64 keys: (float_bits(dist)<<32) | ~idx.
// dist >= 0 so float bits are monotone; ~idx breaks ties toward smaller idx
// (== jnp.argmax first-max). Distance math identical to reference
// (no-FMA ((dx*dx+dy*dy)+dz*dz), fminf). One barrier/step via parity buffers.
// ---------------------------------------------------------------------------
__device__ __forceinline__ unsigned long long u64max(unsigned long long a,
                                                     unsigned long long b)
{
    return (a > b) ? a : b;   // v_cmp_lt_u64 + cndmask, branchless
}

__global__ __launch_bounds__(512) void fps_kernel(
    const float* __restrict__ xyz,
    float* __restrict__ out_nxyz,   // [B,1024,3]
    float* __restrict__ out_idxf)   // [B,1024] (indices stored as float)
{
    __shared__ float sx[NPTS], sy[NPTS], sz[NPTS];
    __shared__ unsigned long long pw[2][8];

    const int tid  = threadIdx.x;
    const int b    = blockIdx.x;
    const int lane = tid & 63;
    const int wid  = tid >> 6;

    const float* bx = xyz + (size_t)b * NPTS * 3;
    for (int p = tid; p < NPTS; p += 512) {
        sx[p] = bx[3 * p];
        sy[p] = bx[3 * p + 1];
        sz[p] = bx[3 * p + 2];
    }
    __syncthreads();

    float rx[8], ry[8], rz[8], dist[8];
#pragma unroll
    for (int j = 0; j < 8; ++j) {
        const int p = tid + j * 512;
        rx[j] = sx[p];
        ry[j] = sy[p];
        rz[j] = sz[p];
        dist[j] = 1e10f;
    }

    if (tid == 0) {
        out_idxf[b * NPT] = 0.0f;
        out_nxyz[(size_t)(b * NPT) * 3 + 0] = sx[0];
        out_nxyz[(size_t)(b * NPT) * 3 + 1] = sy[0];
        out_nxyz[(size_t)(b * NPT) * 3 + 2] = sz[0];
    }

    float lx = sx[0], ly = sy[0], lz = sz[0];

    for (int step = 1; step < NPT; ++step) {
        // ---- local 8-point update + branchless packed argmax ----
        unsigned long long best = 0ULL;
#pragma unroll
        for (int j = 0; j < 8; ++j) {
            const int p = tid + j * 512;
            const float dx = __fsub_rn(rx[j], lx);
            const float dy = __fsub_rn(ry[j], ly);
            const float dz = __fsub_rn(rz[j], lz);
            const float d  = __fadd_rn(__fadd_rn(__fmul_rn(dx, dx), __fmul_rn(dy, dy)),
                                       __fmul_rn(dz, dz));
            const float nd = fminf(dist[j], d);
            dist[j] = nd;
            const unsigned long long key =
                ((unsigned long long)__float_as_uint(nd) << 32) |
                (unsigned int)(~p);
            best = u64max(best, key);
        }
        // ---- wave butterfly max (branchless) ----
#pragma unroll
        for (int off = 1; off < 64; off <<= 1) {
            const unsigned int lo  = (unsigned int)best;
            const unsigned int hi  = (unsigned int)(best >> 32);
            const unsigned int olo = __shfl_xor(lo, off);
            const unsigned int ohi = __shfl_xor(hi, off);
            const unsigned long long o =
                ((unsigned long long)ohi << 32) | olo;
            best = u64max(best, o);
        }
        const int par = step & 1;
        if (lane == 0) pw[par][wid] = best;
        __syncthreads();
        // ---- every thread reduces the 8 wave winners (branchless) ----
        unsigned long long m = pw[par][0];
#pragma unroll
        for (int w = 1; w < 8; ++w) m = u64max(m, pw[par][w]);
        const int ix = (int)(~(unsigned int)m);

        lx = sx[ix];  // broadcast (same address across lanes)
        ly = sy[ix];
        lz = sz[ix];
        if (tid == 0) {
            out_idxf[b * NPT + step] = (float)ix;
            out_nxyz[(size_t)(b * NPT + step) * 3 + 0] = lx;
            out_nxyz[(size_t)(b * NPT + step) * 3 + 1] = ly;
            out_nxyz[(size_t)(b * NPT + step) * 3 + 2] = lz;
        }
        // single barrier per step: next step writes the other pw buffer.
    }
}

// ---------------------------------------------------------------------------
// Dense layer, fully unrolled, activations in REGISTERS (static indices only).
// Weight addresses are wave-uniform with compile-time offsets -> scalar loads
// (s_load_dwordx16) on the scalar pipe, overlapping the VALU FMA stream.
// Accumulation order per output channel: c ascending (same as before).
// ---------------------------------------------------------------------------
template <int CIN, int FOUT>
__device__ __forceinline__ void dense_relu(const float* __restrict__ W,
                                           const float* __restrict__ in,
                                           float* __restrict__ out)
{
#pragma unroll
    for (int f = 0; f < FOUT; ++f) out[f] = 0.0f;
#pragma unroll
    for (int c = 0; c < CIN; ++c) {
        const float xc = in[c];
#pragma unroll
        for (int f = 0; f < FOUT; ++f)
            out[f] = fmaf(xc, W[c * FOUT + f], out[f]);
    }
#pragma unroll
    for (int f = 0; f < FOUT; ++f) out[f] = fmaxf(out[f], 0.0f);
}

// Final layer: output channels processed CH at a time inside a ROLLED chunk
// loop (acc regs reused; register indices are chunk-independent -> static).
// relu + K-lane max-pool butterfly + store per chunk.
template <int CIN, int FOUT, int CH, int K>
__device__ __forceinline__ void dense_pool_store(const float* __restrict__ W,
                                                 const float* __restrict__ in,
                                                 int k, float* __restrict__ outp)
{
#pragma unroll 1
    for (int ch = 0; ch < FOUT / CH; ++ch) {
        const float* __restrict__ Wc = W + ch * CH;
        float acc[CH];
#pragma unroll
        for (int j = 0; j < CH; ++j) acc[j] = 0.0f;
#pragma unroll
        for (int c = 0; c < CIN; ++c) {
            const float xc = in[c];
#pragma unroll
            for (int j = 0; j < CH; ++j)
                acc[j] = fmaf(xc, Wc[c * FOUT + j], acc[j]);
        }
#pragma unroll
        for (int j = 0; j < CH; ++j) acc[j] = fmaxf(acc[j], 0.0f);
        // max-pool across the K-lane neighbor group (butterfly)
#pragma unroll
        for (int off = 1; off < K; off <<= 1) {
#pragma unroll
            for (int j = 0; j < CH; ++j)
                acc[j] = fmaxf(acc[j], __shfl_xor(acc[j], off));
        }
        if (k == 0) {
            float4* o = (float4*)(outp + ch * CH);
#pragma unroll
            for (int j = 0; j < CH / 4; ++j)
                o[j] = make_float4(acc[4 * j + 0], acc[4 * j + 1],
                                   acc[4 * j + 2], acc[4 * j + 3]);
        }
    }
}

// ---------------------------------------------------------------------------
// Per-scale: ball query + gather + 3-layer MLP (register-resident) + max-pool.
// LDS holds only the ball-query neighbor list (NT*4 bytes).
// ---------------------------------------------------------------------------
template <int K, int F0, int F1, int F2, int CH_OFF, int NT>
__global__ __launch_bounds__(NT) void sa_kernel(
    const float* __restrict__ xyz,
    const float* __restrict__ points,
    const float* __restrict__ newxyz,   // read back from d_out region 0
    const float* __restrict__ w0,
    const float* __restrict__ w1,
    const float* __restrict__ w2,
    float* __restrict__ out1,
    float r2)
{
    constexpr int QPW = 64 / K;
    constexpr int NW  = NT / 64;
    constexpr unsigned long long KMASK =
        (K == 64) ? ~0ULL : ((1ULL << K) - 1ULL);

    __shared__ int slist[NT];   // NW * QPW * K == NT

    const int tid  = threadIdx.x;
    const int lane = tid & 63;
    const int wid  = tid >> 6;
    const int k    = lane & (K - 1);
    const int qsub = lane / K;
    const int qid  = (blockIdx.x * NW + wid) * QPW + qsub;
    const int b    = qid >> 10;

    const float qx = newxyz[(size_t)qid * 3 + 0];
    const float qy = newxyz[(size_t)qid * 3 + 1];
    const float qz = newxyz[(size_t)qid * 3 + 2];
    const float* bxyz = xyz + (size_t)b * NPTS * 3;

    // ---- ball query: first K in-ball indices in ascending order ----
    int cnt = 0;
    const int gbase = (wid * QPW + qsub) * K;
    for (int c0 = 0; c0 < NPTS; c0 += K) {
        bool hit = false;
        const int p = c0 + k;
        if (cnt < K) {
            const float dx = __fsub_rn(qx, bxyz[3 * p]);
            const float dy = __fsub_rn(qy, bxyz[3 * p + 1]);
            const float dz = __fsub_rn(qz, bxyz[3 * p + 2]);
            const float d2 = __fadd_rn(__fadd_rn(__fmul_rn(dx, dx), __fmul_rn(dy, dy)),
                                       __fmul_rn(dz, dz));
            hit = d2 < r2;
        }
        const unsigned long long bal = __ballot(hit);
        const unsigned long long gm  = (bal >> (qsub * K)) & KMASK;
        const int pre = __popcll(gm & ((1ULL << k) - 1ULL));
        const int pos = cnt + pre;
        if (hit && pos < K) slist[gbase + pos] = p;
        cnt = min(cnt + (int)__popcll(gm), K);
        if (__all(cnt >= K)) break;
    }
    const int nbr = slist[gbase + ((k < cnt) ? k : 0)];

    // ---- gather: 16 point features + 3 relative xyz into REGISTERS ----
    float a0r[19];
    {
        const float4* prow = (const float4*)(points + ((size_t)b * NPTS + nbr) * 16);
        const float4 p0 = prow[0], p1 = prow[1], p2 = prow[2], p3 = prow[3];
        a0r[0]  = p0.x; a0r[1]  = p0.y; a0r[2]  = p0.z; a0r[3]  = p0.w;
        a0r[4]  = p1.x; a0r[5]  = p1.y; a0r[6]  = p1.z; a0r[7]  = p1.w;
        a0r[8]  = p2.x; a0r[9]  = p2.y; a0r[10] = p2.z; a0r[11] = p2.w;
        a0r[12] = p3.x; a0r[13] = p3.y; a0r[14] = p3.z; a0r[15] = p3.w;
        a0r[16] = __fsub_rn(bxyz[3 * nbr],     qx);
        a0r[17] = __fsub_rn(bxyz[3 * nbr + 1], qy);
        a0r[18] = __fsub_rn(bxyz[3 * nbr + 2], qz);
    }

    // ---- MLP, all register-resident ----
    float h0[F0];
    dense_relu<19, F0>(w0, a0r, h0);
    float h1[F1];
    dense_relu<F0, F1>(w1, h0, h1);
    dense_pool_store<F1, F2, 32, K>(w2, h1, k,
                                    out1 + (size_t)qid * 320 + CH_OFF);
}

// ---------------------------------------------------------------------------
extern "C" void kernel_launch(void* const* d_in, const int* in_sizes, int n_in,
                              void* d_out, int out_size, void* d_ws, size_t ws_size,
                              hipStream_t stream)
{
    const float* xyz    = (const float*)d_in[0];
    const float* points = (const float*)d_in[1];
    const float* w00 = (const float*)d_in[2];
    const float* w01 = (const float*)d_in[3];
    const float* w02 = (const float*)d_in[4];
    const float* w10 = (const float*)d_in[5];
    const float* w11 = (const float*)d_in[6];
    const float* w12 = (const float*)d_in[7];
    const float* w20 = (const float*)d_in[8];
    const float* w21 = (const float*)d_in[9];
    const float* w22 = (const float*)d_in[10];

    float* out       = (float*)d_out;
    float* out_nxyz  = out;                       // 16*1024*3   = 49152
    float* out_feat  = out + 49152;               // 16*1024*320 = 5242880
    float* out_idxf  = out + 49152 + 5242880;     // 16*1024     = 16384

    fps_kernel<<<BATCH, 512, 0, stream>>>(xyz, out_nxyz, out_idxf);

    // scale 0: r=0.1, K=16, MLP 19->32->32->64, CH_OFF 0
    sa_kernel<16, 32, 32, 64, 0, 256><<<1024, 256, 0, stream>>>(
        xyz, points, out_nxyz, w00, w01, w02, out_feat, (float)(0.1 * 0.1));
    // scale 1: r=0.2, K=32, MLP 19->64->64->128, CH_OFF 64
    sa_kernel<32, 64, 64, 128, 64, 128><<<4096, 128, 0, stream>>>(
        xyz, points, out_nxyz, w10, w11, w12, out_feat, (float)(0.2 * 0.2));
    // scale 2: r=0.4, K=64, MLP 19->64->96->128, CH_OFF 192
    sa_kernel<64, 64, 96, 128, 192, 128><<<8192, 128, 0, stream>>>(
        xyz, points, out_nxyz, w20, w21, w22, out_feat, (float)(0.4 * 0.4));
}

// Round 5
// 2008.892 us; speedup vs baseline: 1.8150x; 1.0147x over previous
//
#include <hip/hip_runtime.h>

#define NPTS 4096
#define NPT  1024
#define BATCH 16

// ---------------------------------------------------------------------------
// Farthest point sampling: one block (256 thr / 4 waves) per batch element.
// Coords + running min-dist in registers (16 pts/thread). Branchless packed
// u64 argmax: (float_bits(dist)<<32) | ~idx  (dist>=0 -> monotone bits; ~idx
// breaks ties toward the smaller index == jnp.argmax first-max).
// NO global stores inside the step loop (they would force a vmcnt(0) drain at
// every barrier): chosen indices go to an LDS array; outputs are written once
// at the end. Distance math identical to reference (no-FMA, fminf).
// ---------------------------------------------------------------------------
__device__ __forceinline__ unsigned long long u64max(unsigned long long a,
                                                     unsigned long long b)
{
    return (a > b) ? a : b;   // v_cmp_lt_u64 + cndmask, branchless
}

__global__ __launch_bounds__(256) void fps_kernel(
    const float* __restrict__ xyz,
    float* __restrict__ out_nxyz,   // [B,1024,3]
    float* __restrict__ out_idxf)   // [B,1024] (indices stored as float)
{
    __shared__ float sx[NPTS], sy[NPTS], sz[NPTS];
    __shared__ unsigned long long pw[2][4];
    __shared__ int sidx[NPT];

    const int tid  = threadIdx.x;
    const int b    = blockIdx.x;
    const int lane = tid & 63;
    const int wid  = tid >> 6;

    const float* bx = xyz + (size_t)b * NPTS * 3;
    for (int p = tid; p < NPTS; p += 256) {
        sx[p] = bx[3 * p];
        sy[p] = bx[3 * p + 1];
        sz[p] = bx[3 * p + 2];
    }
    if (tid == 0) sidx[0] = 0;
    __syncthreads();

    float rx[16], ry[16], rz[16], dist[16];
#pragma unroll
    for (int j = 0; j < 16; ++j) {
        const int p = tid + j * 256;
        rx[j] = sx[p];
        ry[j] = sy[p];
        rz[j] = sz[p];
        dist[j] = 1e10f;
    }

    float lx = sx[0], ly = sy[0], lz = sz[0];

    for (int step = 1; step < NPT; ++step) {
        // ---- local 16-point update + branchless packed argmax ----
        unsigned long long best = 0ULL;
#pragma unroll
        for (int j = 0; j < 16; ++j) {
            const int p = tid + j * 256;
            const float dx = __fsub_rn(rx[j], lx);
            const float dy = __fsub_rn(ry[j], ly);
            const float dz = __fsub_rn(rz[j], lz);
            const float d  = __fadd_rn(__fadd_rn(__fmul_rn(dx, dx), __fmul_rn(dy, dy)),
                                       __fmul_rn(dz, dz));
            const float nd = fminf(dist[j], d);
            dist[j] = nd;
            const unsigned long long key =
                ((unsigned long long)__float_as_uint(nd) << 32) |
                (unsigned int)(~p);
            best = u64max(best, key);
        }
        // ---- wave butterfly max (branchless) ----
#pragma unroll
        for (int off = 1; off < 64; off <<= 1) {
            const unsigned int lo  = (unsigned int)best;
            const unsigned int hi  = (unsigned int)(best >> 32);
            const unsigned int olo = __shfl_xor(lo, off);
            const unsigned int ohi = __shfl_xor(hi, off);
            const unsigned long long o =
                ((unsigned long long)ohi << 32) | olo;
            best = u64max(best, o);
        }
        const int par = step & 1;
        if (lane == 0) pw[par][wid] = best;
        __syncthreads();
        // ---- every thread reduces the 4 wave winners (branchless) ----
        unsigned long long m = pw[par][0];
#pragma unroll
        for (int w = 1; w < 4; ++w) m = u64max(m, pw[par][w]);
        const int ix = (int)(~(unsigned int)m);

        lx = sx[ix];  // broadcast (same address across lanes)
        ly = sy[ix];
        lz = sz[ix];
        if (tid == 0) sidx[step] = ix;   // LDS only - no vmcnt at the barrier
        // single barrier per step: next step writes the other pw buffer.
    }
    __syncthreads();

    // ---- cooperative output write (once) ----
    for (int s = tid; s < NPT; s += 256) {
        const int ix = sidx[s];
        out_idxf[b * NPT + s] = (float)ix;
        out_nxyz[(size_t)(b * NPT + s) * 3 + 0] = sx[ix];
        out_nxyz[(size_t)(b * NPT + s) * 3 + 1] = sy[ix];
        out_nxyz[(size_t)(b * NPT + s) * 3 + 2] = sz[ix];
    }
}

// ---------------------------------------------------------------------------
// Dense layer, fully unrolled, activations in REGISTERS (static indices only).
// Weight addresses are wave-uniform with compile-time offsets -> scalar loads
// on the scalar pipe, overlapping the VALU FMA stream.
// Accumulation order per output channel: c ascending (bit-identical).
// ---------------------------------------------------------------------------
template <int CIN, int FOUT>
__device__ __forceinline__ void dense_relu(const float* __restrict__ W,
                                           const float* __restrict__ in,
                                           float* __restrict__ out)
{
#pragma unroll
    for (int f = 0; f < FOUT; ++f) out[f] = 0.0f;
#pragma unroll
    for (int c = 0; c < CIN; ++c) {
        const float xc = in[c];
#pragma unroll
        for (int f = 0; f < FOUT; ++f)
            out[f] = fmaf(xc, W[c * FOUT + f], out[f]);
    }
#pragma unroll
    for (int f = 0; f < FOUT; ++f) out[f] = fmaxf(out[f], 0.0f);
}

// Final layer: output channels processed CH at a time inside a ROLLED chunk
// loop (acc regs reused; register indices chunk-independent -> static).
// relu + K-lane max-pool butterfly + store per chunk.
template <int CIN, int FOUT, int CH, int K>
__device__ __forceinline__ void dense_pool_store(const float* __restrict__ W,
                                                 const float* __restrict__ in,
                                                 int k, float* __restrict__ outp)
{
#pragma unroll 1
    for (int ch = 0; ch < FOUT / CH; ++ch) {
        const float* __restrict__ Wc = W + ch * CH;
        float acc[CH];
#pragma unroll
        for (int j = 0; j < CH; ++j) acc[j] = 0.0f;
#pragma unroll
        for (int c = 0; c < CIN; ++c) {
            const float xc = in[c];
#pragma unroll
            for (int j = 0; j < CH; ++j)
                acc[j] = fmaf(xc, Wc[c * FOUT + j], acc[j]);
        }
#pragma unroll
        for (int j = 0; j < CH; ++j) acc[j] = fmaxf(acc[j], 0.0f);
        // max-pool across the K-lane neighbor group (butterfly)
#pragma unroll
        for (int off = 1; off < K; off <<= 1) {
#pragma unroll
            for (int j = 0; j < CH; ++j)
                acc[j] = fmaxf(acc[j], __shfl_xor(acc[j], off));
        }
        if (k == 0) {
            float4* o = (float4*)(outp + ch * CH);
#pragma unroll
            for (int j = 0; j < CH / 4; ++j)
                o[j] = make_float4(acc[4 * j + 0], acc[4 * j + 1],
                                   acc[4 * j + 2], acc[4 * j + 3]);
        }
    }
}

// ---------------------------------------------------------------------------
// Per-scale: ball query + gather + 3-layer MLP (register-resident) + max-pool.
// __launch_bounds__(NT, 1): allow the full VGPR budget (live set for scale 2
// is ~200 floats) -- at the default heuristic (84 VGPRs) the compiler spilled
// h0/h1 to scratch, which dominated runtime. 2 waves/SIMD, zero spill.
// ---------------------------------------------------------------------------
template <int K, int F0, int F1, int F2, int CH_OFF, int NT>
__global__ __launch_bounds__(NT, 1) void sa_kernel(
    const float* __restrict__ xyz,
    const float* __restrict__ points,
    const float* __restrict__ newxyz,   // read back from d_out region 0
    const float* __restrict__ w0,
    const float* __restrict__ w1,
    const float* __restrict__ w2,
    float* __restrict__ out1,
    float r2)
{
    constexpr int QPW = 64 / K;
    constexpr int NW  = NT / 64;
    constexpr unsigned long long KMASK =
        (K == 64) ? ~0ULL : ((1ULL << K) - 1ULL);

    __shared__ int slist[NT];   // NW * QPW * K == NT

    const int tid  = threadIdx.x;
    const int lane = tid & 63;
    const int wid  = tid >> 6;
    const int k    = lane & (K - 1);
    const int qsub = lane / K;
    const int qid  = (blockIdx.x * NW + wid) * QPW + qsub;
    const int b    = qid >> 10;

    const float qx = newxyz[(size_t)qid * 3 + 0];
    const float qy = newxyz[(size_t)qid * 3 + 1];
    const float qz = newxyz[(size_t)qid * 3 + 2];
    const float* bxyz = xyz + (size_t)b * NPTS * 3;

    // ---- ball query: first K in-ball indices in ascending order ----
    int cnt = 0;
    const int gbase = (wid * QPW + qsub) * K;
    for (int c0 = 0; c0 < NPTS; c0 += K) {
        bool hit = false;
        const int p = c0 + k;
        if (cnt < K) {
            const float dx = __fsub_rn(qx, bxyz[3 * p]);
            const float dy = __fsub_rn(qy, bxyz[3 * p + 1]);
            const float dz = __fsub_rn(qz, bxyz[3 * p + 2]);
            const float d2 = __fadd_rn(__fadd_rn(__fmul_rn(dx, dx), __fmul_rn(dy, dy)),
                                       __fmul_rn(dz, dz));
            hit = d2 < r2;
        }
        const unsigned long long bal = __ballot(hit);
        const unsigned long long gm  = (bal >> (qsub * K)) & KMASK;
        const int pre = __popcll(gm & ((1ULL << k) - 1ULL));
        const int pos = cnt + pre;
        if (hit && pos < K) slist[gbase + pos] = p;
        cnt = min(cnt + (int)__popcll(gm), K);
        if (__all(cnt >= K)) break;
    }
    const int nbr = slist[gbase + ((k < cnt) ? k : 0)];

    // ---- gather: 16 point features + 3 relative xyz into REGISTERS ----
    float a0r[19];
    {
        const float4* prow = (const float4*)(points + ((size_t)b * NPTS + nbr) * 16);
        const float4 p0 = prow[0], p1 = prow[1], p2 = prow[2], p3 = prow[3];
        a0r[0]  = p0.x; a0r[1]  = p0.y; a0r[2]  = p0.z; a0r[3]  = p0.w;
        a0r[4]  = p1.x; a0r[5]  = p1.y; a0r[6]  = p1.z; a0r[7]  = p1.w;
        a0r[8]  = p2.x; a0r[9]  = p2.y; a0r[10] = p2.z; a0r[11] = p2.w;
        a0r[12] = p3.x; a0r[13] = p3.y; a0r[14] = p3.z; a0r[15] = p3.w;
        a0r[16] = __fsub_rn(bxyz[3 * nbr],     qx);
        a0r[17] = __fsub_rn(bxyz[3 * nbr + 1], qy);
        a0r[18] = __fsub_rn(bxyz[3 * nbr + 2], qz);
    }

    // ---- MLP, all register-resident ----
    float h0[F0];
    dense_relu<19, F0>(w0, a0r, h0);
    float h1[F1];
    dense_relu<F0, F1>(w1, h0, h1);
    dense_pool_store<F1, F2, 32, K>(w2, h1, k,
                                    out1 + (size_t)qid * 320 + CH_OFF);
}

// ---------------------------------------------------------------------------
extern "C" void kernel_launch(void* const* d_in, const int* in_sizes, int n_in,
                              void* d_out, int out_size, void* d_ws, size_t ws_size,
                              hipStream_t stream)
{
    const float* xyz    = (const float*)d_in[0];
    const float* points = (const float*)d_in[1];
    const float* w00 = (const float*)d_in[2];
    const float* w01 = (const float*)d_in[3];
    const float* w02 = (const float*)d_in[4];
    const float* w10 = (const float*)d_in[5];
    const float* w11 = (const float*)d_in[6];
    const float* w12 = (const float*)d_in[7];
    const float* w20 = (const float*)d_in[8];
    const float* w21 = (const float*)d_in[9];
    const float* w22 = (const float*)d_in[10];

    float* out       = (float*)d_out;
    float* out_nxyz  = out;                       // 16*1024*3   = 49152
    float* out_feat  = out + 49152;               // 16*1024*320 = 5242880
    float* out_idxf  = out + 49152 + 5242880;     // 16*1024     = 16384

    fps_kernel<<<BATCH, 256, 0, stream>>>(xyz, out_nxyz, out_idxf);

    // scale 0: r=0.1, K=16, MLP 19->32->32->64, CH_OFF 0
    sa_kernel<16, 32, 32, 64, 0, 256><<<1024, 256, 0, stream>>>(
        xyz, points, out_nxyz, w00, w01, w02, out_feat, (float)(0.1 * 0.1));
    // scale 1: r=0.2, K=32, MLP 19->64->64->128, CH_OFF 64
    sa_kernel<32, 64, 64, 128, 64, 128><<<4096, 128, 0, stream>>>(
        xyz, points, out_nxyz, w10, w11, w12, out_feat, (float)(0.2 * 0.2));
    // scale 2: r=0.4, K=64, MLP 19->64->96->128, CH_OFF 192
    sa_kernel<64, 64, 96, 128, 192, 128><<<8192, 128, 0, stream>>>(
        xyz, points, out_nxyz, w20, w21, w22, out_feat, (float)(0.4 * 0.4));
}

// Round 6
// 1819.856 us; speedup vs baseline: 2.0035x; 1.1039x over previous
//
#include <hip/hip_runtime.h>

#define NPTS 4096
#define NPT  1024
#define BATCH 16

// ---------------------------------------------------------------------------
// Farthest point sampling: one block (256 thr / 4 waves) per batch element.
// Per-thread float argmax (branchless cndmask), packed u64 key only for the
// cross-lane phase: (float_bits(dist)<<32) | ~idx  (dist>=0 -> monotone bits;
// ~idx ties toward smaller index == jnp.argmax first-max).
// Wave lane0 PRE-FETCHES the wave winner's coords before the barrier and
// publishes (key,x,y,z); post-barrier threads reduce 4 keys + cndmask-select
// coords -> no winner-dependent LDS read on the critical path.
// Distance math identical to reference (no-FMA ((dx*dx+dy*dy)+dz*dz), fminf).
// ---------------------------------------------------------------------------
__device__ __forceinline__ unsigned long long u64max(unsigned long long a,
                                                     unsigned long long b)
{
    return (a > b) ? a : b;   // v_cmp_lt_u64 + cndmask, branchless
}

__global__ __launch_bounds__(256) void fps_kernel(
    const float* __restrict__ xyz,
    float* __restrict__ out_nxyz,   // [B,1024,3]
    float* __restrict__ out_idxf)   // [B,1024] (indices stored as float)
{
    __shared__ float sx[NPTS], sy[NPTS], sz[NPTS];
    __shared__ unsigned long long pwk[2][4];
    __shared__ float4 pwc[2][4];
    __shared__ int sidx[NPT];

    const int tid  = threadIdx.x;
    const int b    = blockIdx.x;
    const int lane = tid & 63;
    const int wid  = tid >> 6;

    const float* bx = xyz + (size_t)b * NPTS * 3;
    for (int p = tid; p < NPTS; p += 256) {
        sx[p] = bx[3 * p];
        sy[p] = bx[3 * p + 1];
        sz[p] = bx[3 * p + 2];
    }
    if (tid == 0) sidx[0] = 0;
    __syncthreads();

    float rx[16], ry[16], rz[16], dist[16];
#pragma unroll
    for (int j = 0; j < 16; ++j) {
        const int p = tid + j * 256;
        rx[j] = sx[p];
        ry[j] = sy[p];
        rz[j] = sz[p];
        dist[j] = 1e10f;
    }

    float lx = sx[0], ly = sy[0], lz = sz[0];

    for (int step = 1; step < NPT; ++step) {
        // ---- local 16-point update + branchless float argmax ----
        float bv = -1.0f;
        int   bp = 0;
#pragma unroll
        for (int j = 0; j < 16; ++j) {
            const int p = tid + j * 256;
            const float dx = __fsub_rn(rx[j], lx);
            const float dy = __fsub_rn(ry[j], ly);
            const float dz = __fsub_rn(rz[j], lz);
            const float d  = __fadd_rn(__fadd_rn(__fmul_rn(dx, dx), __fmul_rn(dy, dy)),
                                       __fmul_rn(dz, dz));
            const float nd = fminf(dist[j], d);
            dist[j] = nd;
            const bool gt = nd > bv;     // strict: first max within thread
            bv = gt ? nd : bv;
            bp = gt ? p : bp;
        }
        unsigned long long best =
            ((unsigned long long)__float_as_uint(bv) << 32) |
            (unsigned int)(~bp);
        // ---- wave butterfly max (branchless) ----
#pragma unroll
        for (int off = 1; off < 64; off <<= 1) {
            const unsigned int lo  = (unsigned int)best;
            const unsigned int hi  = (unsigned int)(best >> 32);
            const unsigned int olo = __shfl_xor(lo, off);
            const unsigned int ohi = __shfl_xor(hi, off);
            const unsigned long long o =
                ((unsigned long long)ohi << 32) | olo;
            best = u64max(best, o);
        }
        const int par = step & 1;
        if (lane == 0) {
            const int wix = (int)(~(unsigned int)best);
            pwk[par][wid] = best;
            pwc[par][wid] = make_float4(sx[wix], sy[wix], sz[wix], 0.0f);
        }
        __syncthreads();
        // ---- reduce 4 wave winners; select coords via cndmask ----
        unsigned long long m = pwk[par][0];
        float4 c = pwc[par][0];
#pragma unroll
        for (int w = 1; w < 4; ++w) {
            const unsigned long long kw = pwk[par][w];
            const float4 cw = pwc[par][w];
            const bool gt = kw > m;
            m   = gt ? kw : m;
            c.x = gt ? cw.x : c.x;
            c.y = gt ? cw.y : c.y;
            c.z = gt ? cw.z : c.z;
        }
        lx = c.x; ly = c.y; lz = c.z;
        if (tid == 0) sidx[step] = (int)(~(unsigned int)m);  // LDS only
        // single barrier per step: next step writes the other parity buffer.
    }
    __syncthreads();

    // ---- cooperative output write (once) ----
    for (int s = tid; s < NPT; s += 256) {
        const int ix = sidx[s];
        out_idxf[b * NPT + s] = (float)ix;
        out_nxyz[(size_t)(b * NPT + s) * 3 + 0] = sx[ix];
        out_nxyz[(size_t)(b * NPT + s) * 3 + 1] = sy[ix];
        out_nxyz[(size_t)(b * NPT + s) * 3 + 2] = sz[ix];
    }
}

// ---------------------------------------------------------------------------
// Final layer: output channels in chunks of CH inside a ROLLED chunk loop
// (acc regs reused, all register indices static; only pointers are runtime).
// relu + K-lane max-pool butterfly + store per chunk.
// ---------------------------------------------------------------------------
template <int CIN, int FOUT, int CH, int K>
__device__ __forceinline__ void dense_pool_store(const float* __restrict__ W,
                                                 const float* __restrict__ in,
                                                 int k, float* __restrict__ outp)
{
#pragma unroll 1
    for (int ch = 0; ch < FOUT / CH; ++ch) {
        const float* __restrict__ Wc = W + ch * CH;
        float acc[CH];
#pragma unroll
        for (int j = 0; j < CH; ++j) acc[j] = 0.0f;
#pragma unroll
        for (int c = 0; c < CIN; ++c) {
            const float xc = in[c];
#pragma unroll
            for (int j = 0; j < CH; ++j)
                acc[j] = fmaf(xc, Wc[c * FOUT + j], acc[j]);
        }
#pragma unroll
        for (int j = 0; j < CH; ++j) acc[j] = fmaxf(acc[j], 0.0f);
#pragma unroll
        for (int off = 1; off < K; off <<= 1) {
#pragma unroll
            for (int j = 0; j < CH; ++j)
                acc[j] = fmaxf(acc[j], __shfl_xor(acc[j], off));
        }
        if (k == 0) {
            float4* o = (float4*)(outp + ch * CH);
#pragma unroll
            for (int j = 0; j < CH / 4; ++j)
                o[j] = make_float4(acc[4 * j + 0], acc[4 * j + 1],
                                   acc[4 * j + 2], acc[4 * j + 3]);
        }
    }
}

// ---------------------------------------------------------------------------
// Per-scale: ball query + gather + 3-layer MLP + max-pool.
// Layer1->Layer2 FUSED STREAM: rolled loop over F0/16 chunks; each iteration
// produces a fresh static t[16] (19x16 FMA), applies relu, and immediately
// accumulates it into the full static acc1[F1] (16xF1 FMA). Every unrolled
// body is <= ~1.8k instructions and every register index is compile-time
// static -> no scratch spills, no giant-basic-block allocator failure.
// Accumulation order (c ascending per output channel) is bit-identical.
// ---------------------------------------------------------------------------
template <int K, int F0, int F1, int F2, int CH_OFF, int NT>
__global__ __launch_bounds__(NT, 1) void sa_kernel(
    const float* __restrict__ xyz,
    const float* __restrict__ points,
    const float* __restrict__ newxyz,   // read back from d_out region 0
    const float* __restrict__ w0,
    const float* __restrict__ w1,
    const float* __restrict__ w2,
    float* __restrict__ out1,
    float r2)
{
    constexpr int QPW = 64 / K;
    constexpr int NW  = NT / 64;
    constexpr unsigned long long KMASK =
        (K == 64) ? ~0ULL : ((1ULL << K) - 1ULL);

    __shared__ int slist[NT];   // NW * QPW * K == NT

    const int tid  = threadIdx.x;
    const int lane = tid & 63;
    const int wid  = tid >> 6;
    const int k    = lane & (K - 1);
    const int qsub = lane / K;
    const int qid  = (blockIdx.x * NW + wid) * QPW + qsub;
    const int b    = qid >> 10;

    const float qx = newxyz[(size_t)qid * 3 + 0];
    const float qy = newxyz[(size_t)qid * 3 + 1];
    const float qz = newxyz[(size_t)qid * 3 + 2];
    const float* bxyz = xyz + (size_t)b * NPTS * 3;

    // ---- ball query: first K in-ball indices in ascending order ----
    int cnt = 0;
    const int gbase = (wid * QPW + qsub) * K;
    for (int c0 = 0; c0 < NPTS; c0 += K) {
        bool hit = false;
        const int p = c0 + k;
        if (cnt < K) {
            const float dx = __fsub_rn(qx, bxyz[3 * p]);
            const float dy = __fsub_rn(qy, bxyz[3 * p + 1]);
            const float dz = __fsub_rn(qz, bxyz[3 * p + 2]);
            const float d2 = __fadd_rn(__fadd_rn(__fmul_rn(dx, dx), __fmul_rn(dy, dy)),
                                       __fmul_rn(dz, dz));
            hit = d2 < r2;
        }
        const unsigned long long bal = __ballot(hit);
        const unsigned long long gm  = (bal >> (qsub * K)) & KMASK;
        const int pre = __popcll(gm & ((1ULL << k) - 1ULL));
        const int pos = cnt + pre;
        if (hit && pos < K) slist[gbase + pos] = p;
        cnt = min(cnt + (int)__popcll(gm), K);
        if (__all(cnt >= K)) break;
    }
    const int nbr = slist[gbase + ((k < cnt) ? k : 0)];

    // ---- gather: 16 point features + 3 relative xyz into REGISTERS ----
    float a0r[19];
    {
        const float4* prow = (const float4*)(points + ((size_t)b * NPTS + nbr) * 16);
        const float4 p0 = prow[0], p1 = prow[1], p2 = prow[2], p3 = prow[3];
        a0r[0]  = p0.x; a0r[1]  = p0.y; a0r[2]  = p0.z; a0r[3]  = p0.w;
        a0r[4]  = p1.x; a0r[5]  = p1.y; a0r[6]  = p1.z; a0r[7]  = p1.w;
        a0r[8]  = p2.x; a0r[9]  = p2.y; a0r[10] = p2.z; a0r[11] = p2.w;
        a0r[12] = p3.x; a0r[13] = p3.y; a0r[14] = p3.z; a0r[15] = p3.w;
        a0r[16] = __fsub_rn(bxyz[3 * nbr],     qx);
        a0r[17] = __fsub_rn(bxyz[3 * nbr + 1], qy);
        a0r[18] = __fsub_rn(bxyz[3 * nbr + 2], qz);
    }

    // ---- fused layer1 + layer2 stream ----
    float acc1[F1];
#pragma unroll
    for (int f = 0; f < F1; ++f) acc1[f] = 0.0f;

#pragma unroll 1
    for (int ch = 0; ch < F0 / 16; ++ch) {
        // layer-1 chunk: t[j] = relu(sum_c a0r[c] * W0[c][ch*16+j])
        const float* __restrict__ W0c = w0 + ch * 16;
        float t[16];
#pragma unroll
        for (int j = 0; j < 16; ++j) t[j] = 0.0f;
#pragma unroll
        for (int c = 0; c < 19; ++c) {
            const float xc = a0r[c];
#pragma unroll
            for (int j = 0; j < 16; ++j)
                t[j] = fmaf(xc, W0c[c * F0 + j], t[j]);
        }
#pragma unroll
        for (int j = 0; j < 16; ++j) t[j] = fmaxf(t[j], 0.0f);

        // layer-2 stream: acc1[f] += t[i] * W1[ch*16+i][f]
        const float* __restrict__ W1c = w1 + (size_t)ch * 16 * F1;
#pragma unroll
        for (int i = 0; i < 16; ++i) {
            const float xi = t[i];
#pragma unroll
            for (int f = 0; f < F1; ++f)
                acc1[f] = fmaf(xi, W1c[i * F1 + f], acc1[f]);
        }
    }
#pragma unroll
    for (int f = 0; f < F1; ++f) acc1[f] = fmaxf(acc1[f], 0.0f);

    // ---- layer 3 chunked + pool + store ----
    dense_pool_store<F1, F2, 16, K>(w2, acc1, k,
                                    out1 + (size_t)qid * 320 + CH_OFF);
}

// ---------------------------------------------------------------------------
extern "C" void kernel_launch(void* const* d_in, const int* in_sizes, int n_in,
                              void* d_out, int out_size, void* d_ws, size_t ws_size,
                              hipStream_t stream)
{
    const float* xyz    = (const float*)d_in[0];
    const float* points = (const float*)d_in[1];
    const float* w00 = (const float*)d_in[2];
    const float* w01 = (const float*)d_in[3];
    const float* w02 = (const float*)d_in[4];
    const float* w10 = (const float*)d_in[5];
    const float* w11 = (const float*)d_in[6];
    const float* w12 = (const float*)d_in[7];
    const float* w20 = (const float*)d_in[8];
    const float* w21 = (const float*)d_in[9];
    const float* w22 = (const float*)d_in[10];

    float* out       = (float*)d_out;
    float* out_nxyz  = out;                       // 16*1024*3   = 49152
    float* out_feat  = out + 49152;               // 16*1024*320 = 5242880
    float* out_idxf  = out + 49152 + 5242880;     // 16*1024     = 16384

    fps_kernel<<<BATCH, 256, 0, stream>>>(xyz, out_nxyz, out_idxf);

    // scale 0: r=0.1, K=16, MLP 19->32->32->64, CH_OFF 0
    sa_kernel<16, 32, 32, 64, 0, 256><<<1024, 256, 0, stream>>>(
        xyz, points, out_nxyz, w00, w01, w02, out_feat, (float)(0.1 * 0.1));
    // scale 1: r=0.2, K=32, MLP 19->64->64->128, CH_OFF 64
    sa_kernel<32, 64, 64, 128, 64, 128><<<4096, 128, 0, stream>>>(
        xyz, points, out_nxyz, w10, w11, w12, out_feat, (float)(0.2 * 0.2));
    // scale 2: r=0.4, K=64, MLP 19->64->96->128, CH_OFF 192
    sa_kernel<64, 64, 96, 128, 192, 128><<<8192, 128, 0, stream>>>(
        xyz, points, out_nxyz, w20, w21, w22, out_feat, (float)(0.4 * 0.4));
}

// Round 7
// 1686.397 us; speedup vs baseline: 2.1620x; 1.0791x over previous
//
#include <hip/hip_runtime.h>

#define NPTS 4096
#define NPT  1024
#define BATCH 16

// ---------------------------------------------------------------------------
// DPP helpers: VALU-speed cross-lane max-reduce on a packed u64 key
// (float_bits(dist)<<32)|~idx. dist>=0 -> float bits monotone; ~idx breaks
// ties toward the smaller index (== jnp.argmax first-max). Identity 0 loses
// to every real key (lo = ~p != 0 for p <= 4095).
// ---------------------------------------------------------------------------
template <int CTRL>
__device__ __forceinline__ void dpp_keymax(unsigned long long& key)
{
    const int klo = (int)(unsigned int)key;
    const int khi = (int)(unsigned int)(key >> 32);
    const int nlo = __builtin_amdgcn_update_dpp(0, klo, CTRL, 0xF, 0xF, false);
    const int nhi = __builtin_amdgcn_update_dpp(0, khi, CTRL, 0xF, 0xF, false);
    const unsigned long long ok =
        ((unsigned long long)(unsigned int)nhi << 32) | (unsigned int)nlo;
    key = (ok > key) ? ok : key;
}

template <int CTRL>
__device__ __forceinline__ void dpp_keymax_xyz(unsigned long long& key,
                                               float& x, float& y, float& z)
{
    const int klo = (int)(unsigned int)key;
    const int khi = (int)(unsigned int)(key >> 32);
    const int nlo = __builtin_amdgcn_update_dpp(0, klo, CTRL, 0xF, 0xF, false);
    const int nhi = __builtin_amdgcn_update_dpp(0, khi, CTRL, 0xF, 0xF, false);
    const int nx  = __builtin_amdgcn_update_dpp(0, __float_as_int(x), CTRL, 0xF, 0xF, false);
    const int ny  = __builtin_amdgcn_update_dpp(0, __float_as_int(y), CTRL, 0xF, 0xF, false);
    const int nz  = __builtin_amdgcn_update_dpp(0, __float_as_int(z), CTRL, 0xF, 0xF, false);
    const unsigned long long ok =
        ((unsigned long long)(unsigned int)nhi << 32) | (unsigned int)nlo;
    const bool gt = ok > key;
    key = gt ? ok : key;
    x = gt ? __int_as_float(nx) : x;
    y = gt ? __int_as_float(ny) : y;
    z = gt ? __int_as_float(nz) : z;
}

// ---------------------------------------------------------------------------
// Farthest point sampling: one block (256 thr / 4 waves) per batch element.
// Per-thread branchless float argmax over its 16 points; wave reduction via
// DPP row_shr:1/2/4/8 + row_bcast15/31 (result in lane 63, ~100 cyc vs ~700
// for the ds_bpermute shfl butterfly). Lane 63 fetches winner coords and
// publishes {key,x,y,z}; post-barrier each lane reads record lane&3 and
// reduces 4->1 with two quad_perm DPP stages carrying coords. No global
// stores inside the loop (indices go to LDS; outputs written once at end).
// Distance math identical to reference (no-FMA ((dx*dx+dy*dy)+dz*dz), fminf).
// ---------------------------------------------------------------------------
__global__ __launch_bounds__(256) void fps_kernel(
    const float* __restrict__ xyz,
    float* __restrict__ out_nxyz,   // [B,1024,3]
    float* __restrict__ out_idxf)   // [B,1024] (indices stored as float)
{
    __shared__ float sx[NPTS], sy[NPTS], sz[NPTS];
    __shared__ float4 pr0[2][4];    // {key_lo, key_hi, x, y} per wave
    __shared__ float  pr1[2][4];    // z per wave
    __shared__ int sidx[NPT];

    const int tid  = threadIdx.x;
    const int b    = blockIdx.x;
    const int lane = tid & 63;
    const int wid  = tid >> 6;

    const float* bx = xyz + (size_t)b * NPTS * 3;
    for (int p = tid; p < NPTS; p += 256) {
        sx[p] = bx[3 * p];
        sy[p] = bx[3 * p + 1];
        sz[p] = bx[3 * p + 2];
    }
    if (tid == 0) sidx[0] = 0;
    __syncthreads();

    float rx[16], ry[16], rz[16], dist[16];
#pragma unroll
    for (int j = 0; j < 16; ++j) {
        const int p = tid + j * 256;
        rx[j] = sx[p];
        ry[j] = sy[p];
        rz[j] = sz[p];
        dist[j] = 1e10f;
    }

    float lx = sx[0], ly = sy[0], lz = sz[0];

    for (int step = 1; step < NPT; ++step) {
        // ---- local 16-point update + branchless float argmax ----
        float bv = -1.0f;
        int   bp = 0;
#pragma unroll
        for (int j = 0; j < 16; ++j) {
            const int p = tid + j * 256;
            const float dx = __fsub_rn(rx[j], lx);
            const float dy = __fsub_rn(ry[j], ly);
            const float dz = __fsub_rn(rz[j], lz);
            const float d  = __fadd_rn(__fadd_rn(__fmul_rn(dx, dx), __fmul_rn(dy, dy)),
                                       __fmul_rn(dz, dz));
            const float nd = fminf(dist[j], d);
            dist[j] = nd;
            const bool gt = nd > bv;     // strict: first max within thread
            bv = gt ? nd : bv;
            bp = gt ? p : bp;
        }
        unsigned long long key =
            ((unsigned long long)__float_as_uint(bv) << 32) |
            (unsigned int)(~bp);

        // ---- wave max-reduce via DPP (result lands in lane 63) ----
        dpp_keymax<0x111>(key);   // row_shr:1
        dpp_keymax<0x112>(key);   // row_shr:2
        dpp_keymax<0x114>(key);   // row_shr:4
        dpp_keymax<0x118>(key);   // row_shr:8  -> lane15 of each row = row max
        dpp_keymax<0x142>(key);   // row_bcast15
        dpp_keymax<0x143>(key);   // row_bcast31 -> lane63 = wave max

        const int par = step & 1;
        if (lane == 63) {
            const int wix = (int)(~(unsigned int)key);
            pr0[par][wid] = make_float4(
                __int_as_float((int)(unsigned int)key),
                __int_as_float((int)(unsigned int)(key >> 32)),
                sx[wix], sy[wix]);
            pr1[par][wid] = sz[wix];
        }
        __syncthreads();

        // ---- cross-wave: read record lane&3, quad_perm reduce 4 -> 1 ----
        const float4 r  = pr0[par][lane & 3];
        const float  rzz = pr1[par][lane & 3];
        unsigned long long gkey =
            ((unsigned long long)(unsigned int)__float_as_int(r.y) << 32) |
            (unsigned int)__float_as_int(r.x);
        float gx = r.z, gy = r.w, gz = rzz;
        dpp_keymax_xyz<0xB1>(gkey, gx, gy, gz);   // quad_perm [1,0,3,2] (xor1)
        dpp_keymax_xyz<0x4E>(gkey, gx, gy, gz);   // quad_perm [2,3,0,1] (xor2)

        lx = gx; ly = gy; lz = gz;
        if (tid == 0) sidx[step] = (int)(~(unsigned int)gkey);  // LDS only
        // single barrier per step: next step writes the other parity buffer.
    }
    __syncthreads();

    // ---- cooperative output write (once) ----
    for (int s = tid; s < NPT; s += 256) {
        const int ix = sidx[s];
        out_idxf[b * NPT + s] = (float)ix;
        out_nxyz[(size_t)(b * NPT + s) * 3 + 0] = sx[ix];
        out_nxyz[(size_t)(b * NPT + s) * 3 + 1] = sy[ix];
        out_nxyz[(size_t)(b * NPT + s) * 3 + 2] = sz[ix];
    }
}

// ---------------------------------------------------------------------------
// Final layer: output channels in chunks of CH inside a ROLLED chunk loop
// (acc regs reused, all register indices static; only pointers are runtime).
// relu + K-lane max-pool butterfly + store per chunk.
// ---------------------------------------------------------------------------
template <int CIN, int FOUT, int CH, int K>
__device__ __forceinline__ void dense_pool_store(const float* __restrict__ W,
                                                 const float* __restrict__ in,
                                                 int k, float* __restrict__ outp)
{
#pragma unroll 1
    for (int ch = 0; ch < FOUT / CH; ++ch) {
        const float* __restrict__ Wc = W + ch * CH;
        float acc[CH];
#pragma unroll
        for (int j = 0; j < CH; ++j) acc[j] = 0.0f;
#pragma unroll
        for (int c = 0; c < CIN; ++c) {
            const float xc = in[c];
#pragma unroll
            for (int j = 0; j < CH; ++j)
                acc[j] = fmaf(xc, Wc[c * FOUT + j], acc[j]);
        }
#pragma unroll
        for (int j = 0; j < CH; ++j) acc[j] = fmaxf(acc[j], 0.0f);
#pragma unroll
        for (int off = 1; off < K; off <<= 1) {
#pragma unroll
            for (int j = 0; j < CH; ++j)
                acc[j] = fmaxf(acc[j], __shfl_xor(acc[j], off));
        }
        if (k == 0) {
            float4* o = (float4*)(outp + ch * CH);
#pragma unroll
            for (int j = 0; j < CH / 4; ++j)
                o[j] = make_float4(acc[4 * j + 0], acc[4 * j + 1],
                                   acc[4 * j + 2], acc[4 * j + 3]);
        }
    }
}

// ---------------------------------------------------------------------------
// Per-scale: ball query + gather + 3-layer MLP + max-pool.
// Layer1->Layer2 FUSED STREAM: rolled loop over F0/16 chunks; each iteration
// produces a fresh static t[16] (19x16 FMA), applies relu, and immediately
// accumulates it into the full static acc1[F1] (16xF1 FMA). Every unrolled
// body stays small and every register index is compile-time static -> no
// scratch spills. Accumulation order (c ascending per output) bit-identical.
// ---------------------------------------------------------------------------
template <int K, int F0, int F1, int F2, int CH_OFF, int NT>
__global__ __launch_bounds__(NT, 1) void sa_kernel(
    const float* __restrict__ xyz,
    const float* __restrict__ points,
    const float* __restrict__ newxyz,   // read back from d_out region 0
    const float* __restrict__ w0,
    const float* __restrict__ w1,
    const float* __restrict__ w2,
    float* __restrict__ out1,
    float r2)
{
    constexpr int QPW = 64 / K;
    constexpr int NW  = NT / 64;
    constexpr unsigned long long KMASK =
        (K == 64) ? ~0ULL : ((1ULL << K) - 1ULL);

    __shared__ int slist[NT];   // NW * QPW * K == NT

    const int tid  = threadIdx.x;
    const int lane = tid & 63;
    const int wid  = tid >> 6;
    const int k    = lane & (K - 1);
    const int qsub = lane / K;
    const int qid  = (blockIdx.x * NW + wid) * QPW + qsub;
    const int b    = qid >> 10;

    const float qx = newxyz[(size_t)qid * 3 + 0];
    const float qy = newxyz[(size_t)qid * 3 + 1];
    const float qz = newxyz[(size_t)qid * 3 + 2];
    const float* bxyz = xyz + (size_t)b * NPTS * 3;

    // ---- ball query: first K in-ball indices in ascending order ----
    int cnt = 0;
    const int gbase = (wid * QPW + qsub) * K;
    for (int c0 = 0; c0 < NPTS; c0 += K) {
        bool hit = false;
        const int p = c0 + k;
        if (cnt < K) {
            const float dx = __fsub_rn(qx, bxyz[3 * p]);
            const float dy = __fsub_rn(qy, bxyz[3 * p + 1]);
            const float dz = __fsub_rn(qz, bxyz[3 * p + 2]);
            const float d2 = __fadd_rn(__fadd_rn(__fmul_rn(dx, dx), __fmul_rn(dy, dy)),
                                       __fmul_rn(dz, dz));
            hit = d2 < r2;
        }
        const unsigned long long bal = __ballot(hit);
        const unsigned long long gm  = (bal >> (qsub * K)) & KMASK;
        const int pre = __popcll(gm & ((1ULL << k) - 1ULL));
        const int pos = cnt + pre;
        if (hit && pos < K) slist[gbase + pos] = p;
        cnt = min(cnt + (int)__popcll(gm), K);
        if (__all(cnt >= K)) break;
    }
    const int nbr = slist[gbase + ((k < cnt) ? k : 0)];

    // ---- gather: 16 point features + 3 relative xyz into REGISTERS ----
    float a0r[19];
    {
        const float4* prow = (const float4*)(points + ((size_t)b * NPTS + nbr) * 16);
        const float4 p0 = prow[0], p1 = prow[1], p2 = prow[2], p3 = prow[3];
        a0r[0]  = p0.x; a0r[1]  = p0.y; a0r[2]  = p0.z; a0r[3]  = p0.w;
        a0r[4]  = p1.x; a0r[5]  = p1.y; a0r[6]  = p1.z; a0r[7]  = p1.w;
        a0r[8]  = p2.x; a0r[9]  = p2.y; a0r[10] = p2.z; a0r[11] = p2.w;
        a0r[12] = p3.x; a0r[13] = p3.y; a0r[14] = p3.z; a0r[15] = p3.w;
        a0r[16] = __fsub_rn(bxyz[3 * nbr],     qx);
        a0r[17] = __fsub_rn(bxyz[3 * nbr + 1], qy);
        a0r[18] = __fsub_rn(bxyz[3 * nbr + 2], qz);
    }

    // ---- fused layer1 + layer2 stream ----
    float acc1[F1];
#pragma unroll
    for (int f = 0; f < F1; ++f) acc1[f] = 0.0f;

#pragma unroll 1
    for (int ch = 0; ch < F0 / 16; ++ch) {
        // layer-1 chunk: t[j] = relu(sum_c a0r[c] * W0[c][ch*16+j])
        const float* __restrict__ W0c = w0 + ch * 16;
        float t[16];
#pragma unroll
        for (int j = 0; j < 16; ++j) t[j] = 0.0f;
#pragma unroll
        for (int c = 0; c < 19; ++c) {
            const float xc = a0r[c];
#pragma unroll
            for (int j = 0; j < 16; ++j)
                t[j] = fmaf(xc, W0c[c * F0 + j], t[j]);
        }
#pragma unroll
        for (int j = 0; j < 16; ++j) t[j] = fmaxf(t[j], 0.0f);

        // layer-2 stream: acc1[f] += t[i] * W1[ch*16+i][f]
        const float* __restrict__ W1c = w1 + (size_t)ch * 16 * F1;
#pragma unroll
        for (int i = 0; i < 16; ++i) {
            const float xi = t[i];
#pragma unroll
            for (int f = 0; f < F1; ++f)
                acc1[f] = fmaf(xi, W1c[i * F1 + f], acc1[f]);
        }
    }
#pragma unroll
    for (int f = 0; f < F1; ++f) acc1[f] = fmaxf(acc1[f], 0.0f);

    // ---- layer 3 chunked + pool + store ----
    dense_pool_store<F1, F2, 16, K>(w2, acc1, k,
                                    out1 + (size_t)qid * 320 + CH_OFF);
}

// ---------------------------------------------------------------------------
extern "C" void kernel_launch(void* const* d_in, const int* in_sizes, int n_in,
                              void* d_out, int out_size, void* d_ws, size_t ws_size,
                              hipStream_t stream)
{
    const float* xyz    = (const float*)d_in[0];
    const float* points = (const float*)d_in[1];
    const float* w00 = (const float*)d_in[2];
    const float* w01 = (const float*)d_in[3];
    const float* w02 = (const float*)d_in[4];
    const float* w10 = (const float*)d_in[5];
    const float* w11 = (const float*)d_in[6];
    const float* w12 = (const float*)d_in[7];
    const float* w20 = (const float*)d_in[8];
    const float* w21 = (const float*)d_in[9];
    const float* w22 = (const float*)d_in[10];

    float* out       = (float*)d_out;
    float* out_nxyz  = out;                       // 16*1024*3   = 49152
    float* out_feat  = out + 49152;               // 16*1024*320 = 5242880
    float* out_idxf  = out + 49152 + 5242880;     // 16*1024     = 16384

    fps_kernel<<<BATCH, 256, 0, stream>>>(xyz, out_nxyz, out_idxf);

    // scale 0: r=0.1, K=16, MLP 19->32->32->64, CH_OFF 0
    sa_kernel<16, 32, 32, 64, 0, 256><<<1024, 256, 0, stream>>>(
        xyz, points, out_nxyz, w00, w01, w02, out_feat, (float)(0.1 * 0.1));
    // scale 1: r=0.2, K=32, MLP 19->64->64->128, CH_OFF 64
    sa_kernel<32, 64, 64, 128, 64, 128><<<4096, 128, 0, stream>>>(
        xyz, points, out_nxyz, w10, w11, w12, out_feat, (float)(0.2 * 0.2));
    // scale 2: r=0.4, K=64, MLP 19->64->96->128, CH_OFF 192
    sa_kernel<64, 64, 96, 128, 192, 128><<<8192, 128, 0, stream>>>(
        xyz, points, out_nxyz, w20, w21, w22, out_feat, (float)(0.4 * 0.4));
}